// Round 8
// baseline (2539.863 us; speedup 1.0000x reference)
//
#include <hip/hip_runtime.h>
#include <math.h>

#define B 128
#define S 2048
#define V 800
#define E 128
#define H 64
#define NL 3
#define M (B*S)

typedef unsigned short ushort_t;

__device__ __forceinline__ float bf2f(unsigned short u){
  return __uint_as_float(((unsigned int)u) << 16);
}
__device__ __forceinline__ unsigned short f2bf(float f){
  unsigned int u = __float_as_uint(f);
  u += 0x7fff + ((u >> 16) & 1);          // round-to-nearest-even
  return (unsigned short)(u >> 16);
}
__device__ __forceinline__ float fast_tanh(float x){
  float e = __expf(2.f*x);
  return 1.f - 2.f*__builtin_amdgcn_rcpf(e+1.f);
}
__device__ __forceinline__ int clamp_t(int t){
  return t < 0 ? 0 : (t > S-1 ? S-1 : t);
}

// ---- butterfly matvec machinery -------------------------------------------
// Column-stationary: lane j owns h[j]; products use LOCAL h only (no broadcast).
// Slot->output mapping: out(lane, k) = lane ^ G(k), G bijective on 6 bits.
// Tree folds top slot bit per stage; stage xor-mask m == G(folded bit) keeps
// both summands of each fold on the same output row.
//   bit5->1 (quad_perm), bit4->2 (quad_perm), bit3->8 (row_ror:8)  [DPP, VALU]
//   bits 2,1,0 -> 4,16,32  [7 independent ds_bpermute in the tail]
__device__ __host__ constexpr int Gmap(int k){
  return ((k>>5)&1)*1 + ((k>>4)&1)*2 + ((k>>3)&1)*8
       + ((k>>2)&1)*4 + ((k>>1)&1)*16 + (k&1)*32;
}
#define DPP_XOR1 0xB1   // quad_perm [1,0,3,2]
#define DPP_XOR2 0x4E   // quad_perm [2,3,0,1]
#define DPP_ROR8 0x128  // row_ror:8  (== xor 8 within 16-lane rows)
#define DPPF(v, ctrl) __int_as_float(__builtin_amdgcn_update_dpp(0, __float_as_int(v), (ctrl), 0xf, 0xf, false))
__device__ __forceinline__ float bperm(int addr, float v){
  return __int_as_float(__builtin_amdgcn_ds_bpermute(addr, __float_as_int(v)));
}

// 64x64 matvec step: needs locals  float w[64]  (w[k]=W[lane^G(k)][lane]),
// float h (lane-local), int ba[7] (bpermute byte-addrs (lane^G(k))<<2, k=1..7)
#define BDOT(dotv) do {                                                      \
  float p[64];                                                               \
  _Pragma("unroll")                                                          \
  for (int k=0;k<64;++k) p[k] = w[k]*h;                                      \
  _Pragma("unroll")                                                          \
  for (int k=0;k<32;++k) p[k] += DPPF(p[k+32], DPP_XOR1);                    \
  _Pragma("unroll")                                                          \
  for (int k=0;k<16;++k) p[k] += DPPF(p[k+16], DPP_XOR2);                    \
  _Pragma("unroll")                                                          \
  for (int k=0;k<8;++k)  p[k] += DPPF(p[k+8],  DPP_ROR8);                    \
  float f1_ = bperm(ba[0], p[1]), f2_ = bperm(ba[1], p[2]);                  \
  float f3_ = bperm(ba[2], p[3]), f4_ = bperm(ba[3], p[4]);                  \
  float f5_ = bperm(ba[4], p[5]), f6_ = bperm(ba[5], p[6]);                  \
  float f7_ = bperm(ba[6], p[7]);                                            \
  dotv = ((p[0]+f1_)+(f2_+f3_)) + ((f4_+f5_)+(f6_+f7_));                     \
} while(0)

// per-lane scattered W gather (one-time; w_hh is L2-hot after first touch)
#define LOAD_WBFLY(wbase) do {                                               \
  _Pragma("unroll")                                                          \
  for (int k=0;k<64;++k) w[k] = (wbase)[(size_t)(i ^ Gmap(k))*H + i];        \
} while(0)
#define INIT_BA() do {                                                       \
  _Pragma("unroll")                                                          \
  for (int k=1;k<8;++k) ba[k-1] = ((i ^ Gmap(k)) << 2);                      \
} while(0)
// ---------------------------------------------------------------------------

// pre_emb[v][n] = emb[v]·w_ih[0,n,:] + b_ih[0,n] + b_hh[0,n],  n = d*64+i
__global__ __launch_bounds__(128) void k_pre_emb(const float* __restrict__ emb,
    const float* __restrict__ w_ih, const float* __restrict__ b_ih, const float* __restrict__ b_hh,
    float* __restrict__ pe)
{
  const int v = blockIdx.x;
  const int n = threadIdx.x;           // 0..127
  const float* er = emb + (size_t)v*E;
  const float* wr = w_ih + (size_t)n*E;   // layer 0 rows
  float acc = b_ih[n] + b_hh[n];
  #pragma unroll
  for (int e=0;e<E;e+=4){
    float4 ev = *(const float4*)(er+e);
    float4 wv = *(const float4*)(wr+e);
    acc = fmaf(ev.x, wv.x, acc);
    acc = fmaf(ev.y, wv.y, acc);
    acc = fmaf(ev.z, wv.z, acc);
    acc = fmaf(ev.w, wv.w, acc);
  }
  pe[(size_t)v*128 + n] = acc;
}

// partial mean/max pools over S-chunks
__global__ __launch_bounds__(128) void k_pool(const int* __restrict__ x, const float* __restrict__ emb,
      float* __restrict__ psum, float* __restrict__ pmax)
{
  const int b = blockIdx.x, c = blockIdx.y, e = threadIdx.x;
  const int* xb = x + (size_t)b*S + c*(S/16);
  float s=0.f, m=-INFINITY;
  for (int k=0;k<S/16;++k){
    int v = xb[k];
    float val = emb[(size_t)v*E + e];
    s += val; m = fmaxf(m,val);
  }
  psum[((size_t)b*16 + c)*E + e] = s;
  pmax[((size_t)b*16 + c)*E + e] = m;
}

// layer-0 recurrence, fused gather: pre[t] = pe[x[t]] (pe is 409 KB -> L2-hot).
// One wave per (d,b) chain; butterfly dot (no LDS, no broadcast round-trip).
__global__ __attribute__((amdgpu_flat_work_group_size(64,64)))
__attribute__((amdgpu_waves_per_eu(1,1)))
void k_rec0(const int* __restrict__ x,
            const float* __restrict__ pe,
            ushort_t* __restrict__ y,
            const float* __restrict__ w_hh,
            float* __restrict__ hfin)
{
  const int c = blockIdx.x;           // 0..255
  const int d = c >> 7;
  const int b = c & 127;
  const int i = threadIdx.x;          // 0..63
  float w[64];
  int ba[7];
  LOAD_WBFLY(w_hh + (size_t)d*H*H);   // layer 0
  INIT_BA();
  const int* xb = x + (size_t)b*S;
  const float* peb = pe + d*H + i;    // + v*128 per step
  ushort_t* yb = y + (size_t)b*S*(2*H) + d*H + i;
  const int fwd = (d==0);
  const int dt = fwd ? 1 : -1;
  int t = fwd ? 0 : S-1;

  int vx[8];                          // x values for t .. t+7
  #pragma unroll
  for (int k=0;k<8;++k) vx[k] = xb[clamp_t(t + k*dt)];
  float pl[4];                        // pe rows for t .. t+3
  #pragma unroll
  for (int k=0;k<4;++k) pl[k] = peb[(size_t)vx[k]*128];
  float h = 0.f;

#define STEP0(r) do {                                                        \
    float acc = pl[(r)&3];                                                   \
    pl[(r)&3] = peb[(size_t)vx[((r)+4)&7]*128];  /* row for t+4 */           \
    vx[(r)&7] = xb[clamp_t(t + 8*dt)];           /* x for t+8  */            \
    float dotv; BDOT(dotv);                                                  \
    acc += dotv;                                                             \
    h = fast_tanh(acc);                                                      \
    yb[(size_t)t*(2*H)] = f2bf(h);                                           \
    t += dt;                                                                 \
  } while(0)

  for (int tq=0; tq<S; tq+=8){
    STEP0(0); STEP0(1); STEP0(2); STEP0(3);
    STEP0(4); STEP0(5); STEP0(6); STEP0(7);
  }
#undef STEP0
  hfin[((size_t)d*B + b)*H + i] = h;
}

// layers 1,2 recurrence: pre streamed from HBM (134 MB), depth-8 prefetch
// ring; butterfly dot; compile-time layer/write_y.
template<int LAYER, int WRITEY>
__global__ __attribute__((amdgpu_flat_work_group_size(64,64)))
__attribute__((amdgpu_waves_per_eu(1,1)))
void k_rec(const float* __restrict__ pre,
           ushort_t* __restrict__ y,
           const float* __restrict__ w_hh,
           float* __restrict__ hfin)
{
  const int c = blockIdx.x;           // 0..255
  const int d = c >> 7;
  const int b = c & 127;
  const int i = threadIdx.x;          // 0..63
  float w[64];
  int ba[7];
  LOAD_WBFLY(w_hh + (size_t)(LAYER*2+d)*H*H);
  INIT_BA();
  const float* pb = pre + ((size_t)d*M + (size_t)b*S)*H + i;
  ushort_t* yb = y + (size_t)b*S*(2*H) + d*H + i;
  const int fwd = (d==0);
  const int dt = fwd ? 1 : -1;
  int t = fwd ? 0 : S-1;

  float pl[8];                        // pre values for t .. t+7
  #pragma unroll
  for (int k=0;k<8;++k) pl[k] = pb[(size_t)clamp_t(t + k*dt)*H];
  float h = 0.f;

#define STEPR(r) do {                                                        \
    float acc = pl[r];                                                       \
    pl[r] = pb[(size_t)clamp_t(t + 8*dt)*H];     /* value for t+8 */         \
    float dotv; BDOT(dotv);                                                  \
    acc += dotv;                                                             \
    h = fast_tanh(acc);                                                      \
    if (WRITEY) yb[(size_t)t*(2*H)] = f2bf(h);                               \
    t += dt;                                                                 \
  } while(0)

  for (int tq=0; tq<S; tq+=8){
    STEPR(0); STEPR(1); STEPR(2); STEPR(3);
    STEPR(4); STEPR(5); STEPR(6); STEPR(7);
  }
#undef STEPR
  hfin[((size_t)d*B + b)*H + i] = h;
}

// layers 1,2 input projection: [M,128]@[128,128]^T. Yin is bf16, W is fp32.
#define KC 32
__global__ __launch_bounds__(256) void k_gemm(const ushort_t* __restrict__ Yin,
     const float* __restrict__ w_ih, const float* __restrict__ b_ih,
     const float* __restrict__ b_hh, float* __restrict__ pre, int layer)
{
  __shared__ float sY[KC][132];
  __shared__ float sW[KC][132];
  const int tid = threadIdx.x;
  const int m0 = blockIdx.x * 128;
  const int tn = (tid & 15) * 8;
  const int tm = (tid >> 4) * 8;
  float acc[8][8];
  #pragma unroll
  for (int a=0;a<8;++a)
    #pragma unroll
    for (int q=0;q<8;++q) acc[a][q]=0.f;
  const float* Wb = w_ih + (size_t)layer*2*H*E;
  for (int kc=0; kc<E; kc+=KC){
    #pragma unroll
    for (int r=0;r<2;++r){
      int idx = r*256 + tid;     // 0..511
      int ym = idx >> 2;         // 0..127
      int yk = (idx & 3)*8;      // 0,8,16,24
      const ushort_t* p = Yin + (size_t)(m0+ym)*E + kc + yk;
      ushort4 a = *(const ushort4*)p;
      ushort4 bq = *(const ushort4*)(p+4);
      sY[yk+0][ym]=bf2f(a.x);  sY[yk+1][ym]=bf2f(a.y);  sY[yk+2][ym]=bf2f(a.z);  sY[yk+3][ym]=bf2f(a.w);
      sY[yk+4][ym]=bf2f(bq.x); sY[yk+5][ym]=bf2f(bq.y); sY[yk+6][ym]=bf2f(bq.z); sY[yk+7][ym]=bf2f(bq.w);
    }
    #pragma unroll
    for (int r=0;r<4;++r){
      int idx = r*256 + tid;     // 0..1023
      int wn = idx >> 3;         // 0..127
      int wk = (idx & 7)*4;      // 0..28
      float4 v = *(const float4*)(Wb + (size_t)wn*E + kc + wk);
      sW[wk+0][wn]=v.x; sW[wk+1][wn]=v.y; sW[wk+2][wn]=v.z; sW[wk+3][wn]=v.w;
    }
    __syncthreads();
    #pragma unroll 4
    for (int k=0;k<KC;++k){
      float4 a0 = *(const float4*)&sY[k][tm];
      float4 a1 = *(const float4*)&sY[k][tm+4];
      float4 b0 = *(const float4*)&sW[k][tn];
      float4 b1 = *(const float4*)&sW[k][tn+4];
      float am[8]={a0.x,a0.y,a0.z,a0.w,a1.x,a1.y,a1.z,a1.w};
      float bn[8]={b0.x,b0.y,b0.z,b0.w,b1.x,b1.y,b1.z,b1.w};
      #pragma unroll
      for (int mi=0;mi<8;++mi)
        #pragma unroll
        for (int ni=0;ni<8;++ni)
          acc[mi][ni] = fmaf(am[mi], bn[ni], acc[mi][ni]);
    }
    __syncthreads();
  }
  const int d = tn >> 6;
  const int i0 = tn & 63;
  float bias[8];
  #pragma unroll
  for (int ni=0;ni<8;++ni)
    bias[ni] = b_ih[(size_t)(layer*2+d)*H + i0+ni] + b_hh[(size_t)(layer*2+d)*H + i0+ni];
  #pragma unroll
  for (int mi=0;mi<8;++mi){
    size_t off = ((size_t)d*M + (m0+tm+mi))*H + i0;
    float4 o0 = make_float4(acc[mi][0]+bias[0], acc[mi][1]+bias[1], acc[mi][2]+bias[2], acc[mi][3]+bias[3]);
    float4 o1 = make_float4(acc[mi][4]+bias[4], acc[mi][5]+bias[5], acc[mi][6]+bias[6], acc[mi][7]+bias[7]);
    *(float4*)(pre + off)     = o0;
    *(float4*)(pre + off + 4) = o1;
  }
}

// final FC head; also reduces the 16 pool partials. fp32 in/out.
__global__ __launch_bounds__(128) void k_fc(const float* __restrict__ psum, const float* __restrict__ pmax,
    const float* __restrict__ hfin, const float* __restrict__ fc1_w, const float* __restrict__ fc1_b,
    const float* __restrict__ fc2_w, const float* __restrict__ fc2_b, float* __restrict__ out)
{
  const int b = blockIdx.x, tid = threadIdx.x;
  __shared__ __align__(16) float comb[384];
  __shared__ float red[2];
  float s=0.f, m=-INFINITY;
  #pragma unroll
  for (int c=0;c<16;++c){
    s += psum[((size_t)b*16+c)*E + tid];
    m = fmaxf(m, pmax[((size_t)b*16+c)*E + tid]);
  }
  comb[128+tid] = s*(1.f/2048.f);
  comb[256+tid] = m;
  comb[tid] = (tid<64) ? hfin[(size_t)b*H + tid] : hfin[((size_t)B + b)*H + (tid-64)];
  __syncthreads();
  float acc = fc1_b[tid];
  const float4* wrow = (const float4*)(fc1_w + (size_t)tid*384);
  const float4* cb = (const float4*)comb;
  #pragma unroll 8
  for (int k=0;k<96;++k){
    float4 wv = wrow[k]; float4 cv = cb[k];
    acc = fmaf(wv.x,cv.x,acc); acc = fmaf(wv.y,cv.y,acc);
    acc = fmaf(wv.z,cv.z,acc); acc = fmaf(wv.w,cv.w,acc);
  }
  acc = fmaxf(acc, 0.f);
  float p = acc * fc2_w[tid];
  #pragma unroll
  for (int off=32; off>0; off>>=1) p += __shfl_down(p, off);
  if ((tid & 63)==0) red[tid>>6] = p;
  __syncthreads();
  if (tid==0) out[b] = red[0] + red[1] + fc2_b[0];
}

extern "C" void kernel_launch(void* const* d_in, const int* in_sizes, int n_in,
                              void* d_out, int out_size, void* d_ws, size_t ws_size,
                              hipStream_t stream)
{
  const int*   x     = (const int*)  d_in[0];
  const float* emb   = (const float*)d_in[1];
  const float* w_ih  = (const float*)d_in[2];
  const float* w_hh  = (const float*)d_in[3];
  const float* b_ih  = (const float*)d_in[4];
  const float* b_hh  = (const float*)d_in[5];
  const float* fc1_w = (const float*)d_in[6];
  const float* fc1_b = (const float*)d_in[7];
  const float* fc2_w = (const float*)d_in[8];
  const float* fc2_b = (const float*)d_in[9];
  float* out = (float*)d_out;

  // workspace: keep under ~204 MB
  char* ws = (char*)d_ws;
  float*    pre  = (float*)(ws);                                     // 2*M*H f32  = 134.2 MB (layers 1,2 only)
  ushort_t* y    = (ushort_t*)(ws + (size_t)2*M*H*4);                // M*128 bf16 =  67.1 MB
  float*    pe   = (float*)(ws + (size_t)2*M*H*4 + (size_t)M*128*2); // V*128 f32
  float*    psum = pe   + (size_t)V*128;                             // B*16*E f32
  float*    pmax = psum + (size_t)B*16*E;                            // B*16*E f32
  float*    hfin = pmax + (size_t)B*16*E;                            // 2*B*H f32

  k_pre_emb<<<V, 128, 0, stream>>>(emb, w_ih, b_ih, b_hh, pe);
  k_pool<<<dim3(B,16), 128, 0, stream>>>(x, emb, psum, pmax);
  k_rec0<<<256, 64, 0, stream>>>(x, pe, y, w_hh, hfin);
  k_gemm<<<M/128, 256, 0, stream>>>(y, w_ih, b_ih, b_hh, pre, 1);
  k_rec<1,1><<<256, 64, 0, stream>>>(pre, y, w_hh, hfin);
  k_gemm<<<M/128, 256, 0, stream>>>(y, w_ih, b_ih, b_hh, pre, 2);
  k_rec<2,0><<<256, 64, 0, stream>>>(pre, y, w_hh, hfin);
  k_fc<<<B, 128, 0, stream>>>(psum, pmax, hfin, fc1_w, fc1_b, fc2_w, fc2_b, out);
}

// Round 9
// 1654.947 us; speedup vs baseline: 1.5347x; 1.5347x over previous
//
#include <hip/hip_runtime.h>
#include <math.h>

#define B 128
#define S 2048
#define V 800
#define E 128
#define H 64
#define NL 3
#define M (B*S)

typedef unsigned short ushort_t;

__device__ __forceinline__ float bf2f(unsigned short u){
  return __uint_as_float(((unsigned int)u) << 16);
}
__device__ __forceinline__ unsigned short f2bf(float f){
  unsigned int u = __float_as_uint(f);
  u += 0x7fff + ((u >> 16) & 1);          // round-to-nearest-even
  return (unsigned short)(u >> 16);
}
__device__ __forceinline__ float fast_tanh(float x){
  float e = __expf(2.f*x);
  return 1.f - 2.f*__builtin_amdgcn_rcpf(e+1.f);
}
__device__ __forceinline__ int clamp_t(int t){
  return t < 0 ? 0 : (t > S-1 ? S-1 : t);
}

// ---- 8x8-blocked butterfly matvec ----------------------------------------
// Lane l owns h[l]. Per step, lane l computes partials for the 8 rows
// {l ^ G8(k)} over its 8-column block {c : c bits{0,1,3} == l bits{0,1,3}}.
// Coverage: for any (row r, col c) the covering lane l has bits{2,4,5}=r's,
// bits{0,1,3}=c's -> unique. Fold stage for slot-bit b uses xor-mask G8(b):
// partner's p[k|b] holds row (l^m)^G8(k|b) = l^G8(k) -> same row, disjoint
// column blocks. After 3 folds p0 = full row-l sum. Machinery (G-map proof,
// DPP_ROR8/XOR2/XOR1, 64-lane ds_bpermute) correctness-proven in round 8.
__device__ __host__ constexpr int G8(int k){
  return (k&1)*1 + ((k>>1)&1)*2 + ((k>>2)&1)*8;
}
__device__ __forceinline__ int colof(int l, int j){
  return (l & 0x0B) | ((j&1)<<2) | (((j>>1)&1)<<4) | (((j>>2)&1)<<5);
}
#define DPP_XOR1 0xB1   // quad_perm [1,0,3,2]
#define DPP_XOR2 0x4E   // quad_perm [2,3,0,1]
#define DPP_ROR8 0x128  // row_ror:8 == xor8 within 16-lane rows
#define DPPF(v, ctrl) __int_as_float(__builtin_amdgcn_update_dpp(0, __float_as_int(v), (ctrl), 0xf, 0xf, false))
__device__ __forceinline__ float bperm(int addr, float v){
  return __int_as_float(__builtin_amdgcn_ds_bpermute(addr, __float_as_int(v)));
}

// 8 fmas (one gathered h value against one W-tile column), 8 indep chains
#define DOTJ(jj, hvj)                                                        \
  p0_=fmaf(w[0*8+jj],hvj,p0_); p1_=fmaf(w[1*8+jj],hvj,p1_);                  \
  p2_=fmaf(w[2*8+jj],hvj,p2_); p3_=fmaf(w[3*8+jj],hvj,p3_);                  \
  p4_=fmaf(w[4*8+jj],hvj,p4_); p5_=fmaf(w[5*8+jj],hvj,p5_);                  \
  p6_=fmaf(w[6*8+jj],hvj,p6_); p7_=fmaf(w[7*8+jj],hvj,p7_);

// one recurrence step body: gather 8 h vals (one DS round), 64-fma tile dot
// (acc pre-seeded into p0), 3-stage DPP fold, tanh. Updates h in place.
#define BSTEP(acc_expr)                                                      \
  {                                                                          \
    float hv0_=bperm(ba[0],h), hv1_=bperm(ba[1],h);                          \
    float hv2_=bperm(ba[2],h), hv3_=bperm(ba[3],h);                          \
    float hv4_=bperm(ba[4],h), hv5_=bperm(ba[5],h);                          \
    float hv6_=bperm(ba[6],h), hv7_=bperm(ba[7],h);                          \
    float p0_=(acc_expr), p1_=0.f,p2_=0.f,p3_=0.f,p4_=0.f,p5_=0.f,p6_=0.f,p7_=0.f; \
    DOTJ(0,hv0_); DOTJ(1,hv1_); DOTJ(2,hv2_); DOTJ(3,hv3_);                  \
    DOTJ(4,hv4_); DOTJ(5,hv5_); DOTJ(6,hv6_); DOTJ(7,hv7_);                  \
    p0_ += DPPF(p4_, DPP_ROR8); p1_ += DPPF(p5_, DPP_ROR8);                  \
    p2_ += DPPF(p6_, DPP_ROR8); p3_ += DPPF(p7_, DPP_ROR8);                  \
    p0_ += DPPF(p2_, DPP_XOR2); p1_ += DPPF(p3_, DPP_XOR2);                  \
    p0_ += DPPF(p1_, DPP_XOR1);                                              \
    h = fast_tanh(p0_);                                                      \
  }

// one-time per-lane W-tile gather (L2-hot) + bpermute byte addrs
#define LOAD_W8(wbase) do {                                                  \
  _Pragma("unroll")                                                          \
  for (int k=0;k<8;++k)                                                      \
    _Pragma("unroll")                                                        \
    for (int j=0;j<8;++j)                                                    \
      w[k*8+j] = (wbase)[(size_t)(i ^ G8(k))*H + colof(i,j)];                \
  _Pragma("unroll")                                                          \
  for (int j=0;j<8;++j) ba[j] = colof(i,j) << 2;                             \
} while(0)
// ---------------------------------------------------------------------------

// pre_emb[v][n] = emb[v]·w_ih[0,n,:] + b_ih[0,n] + b_hh[0,n],  n = d*64+i
__global__ __launch_bounds__(128) void k_pre_emb(const float* __restrict__ emb,
    const float* __restrict__ w_ih, const float* __restrict__ b_ih, const float* __restrict__ b_hh,
    float* __restrict__ pe)
{
  const int v = blockIdx.x;
  const int n = threadIdx.x;           // 0..127
  const float* er = emb + (size_t)v*E;
  const float* wr = w_ih + (size_t)n*E;   // layer 0 rows
  float acc = b_ih[n] + b_hh[n];
  #pragma unroll
  for (int e=0;e<E;e+=4){
    float4 ev = *(const float4*)(er+e);
    float4 wv = *(const float4*)(wr+e);
    acc = fmaf(ev.x, wv.x, acc);
    acc = fmaf(ev.y, wv.y, acc);
    acc = fmaf(ev.z, wv.z, acc);
    acc = fmaf(ev.w, wv.w, acc);
  }
  pe[(size_t)v*128 + n] = acc;
}

// partial mean/max pools over S-chunks
__global__ __launch_bounds__(128) void k_pool(const int* __restrict__ x, const float* __restrict__ emb,
      float* __restrict__ psum, float* __restrict__ pmax)
{
  const int b = blockIdx.x, c = blockIdx.y, e = threadIdx.x;
  const int* xb = x + (size_t)b*S + c*(S/16);
  float s=0.f, m=-INFINITY;
  for (int k=0;k<S/16;++k){
    int v = xb[k];
    float val = emb[(size_t)v*E + e];
    s += val; m = fmaxf(m,val);
  }
  psum[((size_t)b*16 + c)*E + e] = s;
  pmax[((size_t)b*16 + c)*E + e] = m;
}

// layer-0 recurrence, fused gather: pre[t] = pe[x[t]] (pe is 409 KB -> L2-hot).
// One wave per (d,b) chain; 8x8 butterfly dot (no LDS round-trip).
__global__ __attribute__((amdgpu_flat_work_group_size(64,64)))
__attribute__((amdgpu_waves_per_eu(1,1)))
void k_rec0(const int* __restrict__ x,
            const float* __restrict__ pe,
            ushort_t* __restrict__ y,
            const float* __restrict__ w_hh,
            float* __restrict__ hfin)
{
  const int c = blockIdx.x;           // 0..255
  const int d = c >> 7;
  const int b = c & 127;
  const int i = threadIdx.x;          // 0..63
  float w[64];
  int ba[8];
  LOAD_W8(w_hh + (size_t)d*H*H);      // layer 0
  const int* xb = x + (size_t)b*S;
  const float* peb = pe + d*H + i;    // + v*128 per step
  ushort_t* yb = y + (size_t)b*S*(2*H) + d*H + i;
  const int fwd = (d==0);
  const int dt = fwd ? 1 : -1;
  int t = fwd ? 0 : S-1;

  int vx[8];                          // x values for t .. t+7
  #pragma unroll
  for (int k=0;k<8;++k) vx[k] = xb[clamp_t(t + k*dt)];
  float pl[4];                        // pe rows for t .. t+3
  #pragma unroll
  for (int k=0;k<4;++k) pl[k] = peb[(size_t)vx[k]*128];
  float h = 0.f;

#define STEP0(r) do {                                                        \
    float acc = pl[(r)&3];                                                   \
    pl[(r)&3] = peb[(size_t)vx[((r)+4)&7]*128];  /* row for t+4 */           \
    vx[(r)&7] = xb[clamp_t(t + 8*dt)];           /* x for t+8  */            \
    BSTEP(acc);                                                              \
    yb[(size_t)t*(2*H)] = f2bf(h);                                           \
    t += dt;                                                                 \
  } while(0)

  for (int tq=0; tq<S; tq+=8){
    STEP0(0); STEP0(1); STEP0(2); STEP0(3);
    STEP0(4); STEP0(5); STEP0(6); STEP0(7);
  }
#undef STEP0
  hfin[((size_t)d*B + b)*H + i] = h;
}

// layers 1,2 recurrence: pre streamed from HBM (134 MB), depth-8 prefetch
// ring; 8x8 butterfly dot; compile-time layer/write_y.
template<int LAYER, int WRITEY>
__global__ __attribute__((amdgpu_flat_work_group_size(64,64)))
__attribute__((amdgpu_waves_per_eu(1,1)))
void k_rec(const float* __restrict__ pre,
           ushort_t* __restrict__ y,
           const float* __restrict__ w_hh,
           float* __restrict__ hfin)
{
  const int c = blockIdx.x;           // 0..255
  const int d = c >> 7;
  const int b = c & 127;
  const int i = threadIdx.x;          // 0..63
  float w[64];
  int ba[8];
  LOAD_W8(w_hh + (size_t)(LAYER*2+d)*H*H);
  const float* pb = pre + ((size_t)d*M + (size_t)b*S)*H + i;
  ushort_t* yb = y + (size_t)b*S*(2*H) + d*H + i;
  const int fwd = (d==0);
  const int dt = fwd ? 1 : -1;
  int t = fwd ? 0 : S-1;

  float pl[8];                        // pre values for t .. t+7
  #pragma unroll
  for (int k=0;k<8;++k) pl[k] = pb[(size_t)clamp_t(t + k*dt)*H];
  float h = 0.f;

#define STEPR(r) do {                                                        \
    float acc = pl[r];                                                       \
    pl[r] = pb[(size_t)clamp_t(t + 8*dt)*H];     /* value for t+8 */         \
    BSTEP(acc);                                                              \
    if (WRITEY) yb[(size_t)t*(2*H)] = f2bf(h);                               \
    t += dt;                                                                 \
  } while(0)

  for (int tq=0; tq<S; tq+=8){
    STEPR(0); STEPR(1); STEPR(2); STEPR(3);
    STEPR(4); STEPR(5); STEPR(6); STEPR(7);
  }
#undef STEPR
  hfin[((size_t)d*B + b)*H + i] = h;
}

// layers 1,2 input projection: [M,128]@[128,128]^T. Yin is bf16, W is fp32.
#define KC 32
__global__ __launch_bounds__(256) void k_gemm(const ushort_t* __restrict__ Yin,
     const float* __restrict__ w_ih, const float* __restrict__ b_ih,
     const float* __restrict__ b_hh, float* __restrict__ pre, int layer)
{
  __shared__ float sY[KC][132];
  __shared__ float sW[KC][132];
  const int tid = threadIdx.x;
  const int m0 = blockIdx.x * 128;
  const int tn = (tid & 15) * 8;
  const int tm = (tid >> 4) * 8;
  float acc[8][8];
  #pragma unroll
  for (int a=0;a<8;++a)
    #pragma unroll
    for (int q=0;q<8;++q) acc[a][q]=0.f;
  const float* Wb = w_ih + (size_t)layer*2*H*E;
  for (int kc=0; kc<E; kc+=KC){
    #pragma unroll
    for (int r=0;r<2;++r){
      int idx = r*256 + tid;     // 0..511
      int ym = idx >> 2;         // 0..127
      int yk = (idx & 3)*8;      // 0,8,16,24
      const ushort_t* p = Yin + (size_t)(m0+ym)*E + kc + yk;
      ushort4 a = *(const ushort4*)p;
      ushort4 bq = *(const ushort4*)(p+4);
      sY[yk+0][ym]=bf2f(a.x);  sY[yk+1][ym]=bf2f(a.y);  sY[yk+2][ym]=bf2f(a.z);  sY[yk+3][ym]=bf2f(a.w);
      sY[yk+4][ym]=bf2f(bq.x); sY[yk+5][ym]=bf2f(bq.y); sY[yk+6][ym]=bf2f(bq.z); sY[yk+7][ym]=bf2f(bq.w);
    }
    #pragma unroll
    for (int r=0;r<4;++r){
      int idx = r*256 + tid;     // 0..1023
      int wn = idx >> 3;         // 0..127
      int wk = (idx & 7)*4;      // 0..28
      float4 v = *(const float4*)(Wb + (size_t)wn*E + kc + wk);
      sW[wk+0][wn]=v.x; sW[wk+1][wn]=v.y; sW[wk+2][wn]=v.z; sW[wk+3][wn]=v.w;
    }
    __syncthreads();
    #pragma unroll 4
    for (int k=0;k<KC;++k){
      float4 a0 = *(const float4*)&sY[k][tm];
      float4 a1 = *(const float4*)&sY[k][tm+4];
      float4 b0 = *(const float4*)&sW[k][tn];
      float4 b1 = *(const float4*)&sW[k][tn+4];
      float am[8]={a0.x,a0.y,a0.z,a0.w,a1.x,a1.y,a1.z,a1.w};
      float bn[8]={b0.x,b0.y,b0.z,b0.w,b1.x,b1.y,b1.z,b1.w};
      #pragma unroll
      for (int mi=0;mi<8;++mi)
        #pragma unroll
        for (int ni=0;ni<8;++ni)
          acc[mi][ni] = fmaf(am[mi], bn[ni], acc[mi][ni]);
    }
    __syncthreads();
  }
  const int d = tn >> 6;
  const int i0 = tn & 63;
  float bias[8];
  #pragma unroll
  for (int ni=0;ni<8;++ni)
    bias[ni] = b_ih[(size_t)(layer*2+d)*H + i0+ni] + b_hh[(size_t)(layer*2+d)*H + i0+ni];
  #pragma unroll
  for (int mi=0;mi<8;++mi){
    size_t off = ((size_t)d*M + (m0+tm+mi))*H + i0;
    float4 o0 = make_float4(acc[mi][0]+bias[0], acc[mi][1]+bias[1], acc[mi][2]+bias[2], acc[mi][3]+bias[3]);
    float4 o1 = make_float4(acc[mi][4]+bias[4], acc[mi][5]+bias[5], acc[mi][6]+bias[6], acc[mi][7]+bias[7]);
    *(float4*)(pre + off)     = o0;
    *(float4*)(pre + off + 4) = o1;
  }
}

// final FC head; also reduces the 16 pool partials. fp32 in/out.
__global__ __launch_bounds__(128) void k_fc(const float* __restrict__ psum, const float* __restrict__ pmax,
    const float* __restrict__ hfin, const float* __restrict__ fc1_w, const float* __restrict__ fc1_b,
    const float* __restrict__ fc2_w, const float* __restrict__ fc2_b, float* __restrict__ out)
{
  const int b = blockIdx.x, tid = threadIdx.x;
  __shared__ __align__(16) float comb[384];
  __shared__ float red[2];
  float s=0.f, m=-INFINITY;
  #pragma unroll
  for (int c=0;c<16;++c){
    s += psum[((size_t)b*16+c)*E + tid];
    m = fmaxf(m, pmax[((size_t)b*16+c)*E + tid]);
  }
  comb[128+tid] = s*(1.f/2048.f);
  comb[256+tid] = m;
  comb[tid] = (tid<64) ? hfin[(size_t)b*H + tid] : hfin[((size_t)B + b)*H + (tid-64)];
  __syncthreads();
  float acc = fc1_b[tid];
  const float4* wrow = (const float4*)(fc1_w + (size_t)tid*384);
  const float4* cb = (const float4*)comb;
  #pragma unroll 8
  for (int k=0;k<96;++k){
    float4 wv = wrow[k]; float4 cv = cb[k];
    acc = fmaf(wv.x,cv.x,acc); acc = fmaf(wv.y,cv.y,acc);
    acc = fmaf(wv.z,cv.z,acc); acc = fmaf(wv.w,cv.w,acc);
  }
  acc = fmaxf(acc, 0.f);
  float p = acc * fc2_w[tid];
  #pragma unroll
  for (int off=32; off>0; off>>=1) p += __shfl_down(p, off);
  if ((tid & 63)==0) red[tid>>6] = p;
  __syncthreads();
  if (tid==0) out[b] = red[0] + red[1] + fc2_b[0];
}

extern "C" void kernel_launch(void* const* d_in, const int* in_sizes, int n_in,
                              void* d_out, int out_size, void* d_ws, size_t ws_size,
                              hipStream_t stream)
{
  const int*   x     = (const int*)  d_in[0];
  const float* emb   = (const float*)d_in[1];
  const float* w_ih  = (const float*)d_in[2];
  const float* w_hh  = (const float*)d_in[3];
  const float* b_ih  = (const float*)d_in[4];
  const float* b_hh  = (const float*)d_in[5];
  const float* fc1_w = (const float*)d_in[6];
  const float* fc1_b = (const float*)d_in[7];
  const float* fc2_w = (const float*)d_in[8];
  const float* fc2_b = (const float*)d_in[9];
  float* out = (float*)d_out;

  // workspace: keep under ~204 MB
  char* ws = (char*)d_ws;
  float*    pre  = (float*)(ws);                                     // 2*M*H f32  = 134.2 MB (layers 1,2 only)
  ushort_t* y    = (ushort_t*)(ws + (size_t)2*M*H*4);                // M*128 bf16 =  67.1 MB
  float*    pe   = (float*)(ws + (size_t)2*M*H*4 + (size_t)M*128*2); // V*128 f32
  float*    psum = pe   + (size_t)V*128;                             // B*16*E f32
  float*    pmax = psum + (size_t)B*16*E;                            // B*16*E f32
  float*    hfin = pmax + (size_t)B*16*E;                            // 2*B*H f32

  k_pre_emb<<<V, 128, 0, stream>>>(emb, w_ih, b_ih, b_hh, pe);
  k_pool<<<dim3(B,16), 128, 0, stream>>>(x, emb, psum, pmax);
  k_rec0<<<256, 64, 0, stream>>>(x, pe, y, w_hh, hfin);
  k_gemm<<<M/128, 256, 0, stream>>>(y, w_ih, b_ih, b_hh, pre, 1);
  k_rec<1,1><<<256, 64, 0, stream>>>(pre, y, w_hh, hfin);
  k_gemm<<<M/128, 256, 0, stream>>>(y, w_ih, b_ih, b_hh, pre, 2);
  k_rec<2,0><<<256, 64, 0, stream>>>(pre, y, w_hh, hfin);
  k_fc<<<B, 128, 0, stream>>>(psum, pmax, hfin, fc1_w, fc1_b, fc2_w, fc2_b, out);
}

// Round 11
// 1580.468 us; speedup vs baseline: 1.6070x; 1.0471x over previous
//
#include <hip/hip_runtime.h>
#include <math.h>

#define B 128
#define S 2048
#define V 800
#define E 128
#define H 64
#define NL 3
#define M (B*S)

typedef unsigned short ushort_t;

__device__ __forceinline__ float bf2f(unsigned short u){
  return __uint_as_float(((unsigned int)u) << 16);
}
__device__ __forceinline__ unsigned short f2bf(float f){
  unsigned int u = __float_as_uint(f);
  u += 0x7fff + ((u >> 16) & 1);          // round-to-nearest-even
  return (unsigned short)(u >> 16);
}
__device__ __forceinline__ float fast_tanh(float x){
  float e = __expf(2.f*x);
  return 1.f - 2.f*__builtin_amdgcn_rcpf(e+1.f);
}
__device__ __forceinline__ int clamp_t(int t){
  return t < 0 ? 0 : (t > S-1 ? S-1 : t);
}

// ---- all-VALU 8x8 butterfly matvec ----------------------------------------
// Lane l owns h[l]. Rows per lane: l ^ G(k), G(k) = (k&3)|((k&4)<<2) over
// span{1,2,16}. Cols per lane: preserve bits{0,1,4}; spread bits{2,3} (rot4
// orbit) and bit5 (permlane32_swap). Folds xor1/xor2 via quad_perm DPP
// (proven R8/R9) + xor16 via permlane16_swap. R10's inline-asm swaps had
// register-aliasing-dependent semantics (both operands written; calibration
// site and use site could allocate differently) -> replaced with the
// __builtin_amdgcn_permlane*_swap pair-returning builtins (deterministic SSA
// semantics, guide T12). Calibration (lane-id markers through the SAME
// builtin + per-lane pick) still absorbs row-pairing conventions.
// Fallback: R8/R9-proven ds_bpermute for any missing builtin.
#define DPP_XOR1 0xB1    // quad_perm [1,0,3,2]
#define DPP_XOR2 0x4E    // quad_perm [2,3,0,1]
#define DPP_ROR4  0x124  // row_ror:4
#define DPP_ROR8  0x128  // row_ror:8
#define DPP_ROR12 0x12C  // row_ror:12
#define DPPI(v, ctrl) __builtin_amdgcn_update_dpp(0, (v), (ctrl), 0xf, 0xf, false)
#define DPPF(v, ctrl) __int_as_float(DPPI(__float_as_int(v), (ctrl)))
__device__ __forceinline__ float bperm(int addr, float v){
  return __int_as_float(__builtin_amdgcn_ds_bpermute(addr, __float_as_int(v)));
}
__device__ __host__ __forceinline__ constexpr int Gmask(int k){
  return (k & 3) | ((k & 4) << 2);      // {0,1,2,3,16,17,18,19}
}

#if __has_builtin(__builtin_amdgcn_permlane32_swap)
#define HAVE_PL32 1
#else
#define HAVE_PL32 0
#endif
#if __has_builtin(__builtin_amdgcn_permlane16_swap)
#define HAVE_PL16 1
#else
#define HAVE_PL16 0
#endif

#if HAVE_PL32
#define XOR32F(x) ({ auto r_ = __builtin_amdgcn_permlane32_swap(__float_as_uint(x), __float_as_uint(x), false, false); \
                     __uint_as_float(pick32 ? r_[0] : r_[1]); })
#else
#define XOR32F(x) bperm(ba32, (x))
#endif
#if HAVE_PL16
#define XOR16F(x) ({ auto r_ = __builtin_amdgcn_permlane16_swap(__float_as_uint(x), __float_as_uint(x), false, false); \
                     __uint_as_float(pick16 ? r_[0] : r_[1]); })
#else
#define XOR16F(x) bperm(ba16, (x))
#endif

// Calibration + W-tile load. Uses locals: w[64], pick16, pick32, ba16, ba32.
// cm_[j] = true source lane of gather op j at this lane (marker-derived, so
// the W layout is self-consistent with whatever the hardware ops do).
#define CALIB_AND_LOAD_W(wbase) do {                                         \
  int mk_ = i;                                                               \
  int g32m_;                                                                 \
  if (HAVE_PL32) {                                                           \
    auto r_ = __builtin_amdgcn_permlane32_swap((unsigned)mk_, (unsigned)mk_, false, false); \
    pick32 = ((int)r_[0] == (mk_ ^ 32));                                     \
    g32m_ = pick32 ? (int)r_[0] : (int)r_[1];                                \
  } else {                                                                   \
    g32m_ = mk_ ^ 32;            /* bperm path pulls exactly lane^32 */      \
  }                                                                          \
  if (HAVE_PL16) {                                                           \
    auto r_ = __builtin_amdgcn_permlane16_swap((unsigned)mk_, (unsigned)mk_, false, false); \
    pick16 = ((int)r_[0] == (mk_ ^ 16));                                     \
  }                                                                          \
  int cm_[8];                                                                \
  cm_[0]=mk_;   cm_[1]=DPPI(mk_,DPP_ROR4);                                   \
  cm_[2]=DPPI(mk_,DPP_ROR8);  cm_[3]=DPPI(mk_,DPP_ROR12);                    \
  cm_[4]=g32m_; cm_[5]=DPPI(g32m_,DPP_ROR4);                                 \
  cm_[6]=DPPI(g32m_,DPP_ROR8); cm_[7]=DPPI(g32m_,DPP_ROR12);                 \
  _Pragma("unroll")                                                          \
  for (int k=0;k<8;++k)                                                      \
    _Pragma("unroll")                                                        \
    for (int j=0;j<8;++j)                                                    \
      w[k*8+j] = (wbase)[(size_t)(i ^ Gmask(k))*H + cm_[j]];                 \
} while(0)

// 8 fmas (one gathered h value against one W-tile column), 8 indep chains
#define DOTJ(jj, hvj)                                                        \
  p0_=fmaf(w[0*8+jj],hvj,p0_); p1_=fmaf(w[1*8+jj],hvj,p1_);                  \
  p2_=fmaf(w[2*8+jj],hvj,p2_); p3_=fmaf(w[3*8+jj],hvj,p3_);                  \
  p4_=fmaf(w[4*8+jj],hvj,p4_); p5_=fmaf(w[5*8+jj],hvj,p5_);                  \
  p6_=fmaf(w[6*8+jj],hvj,p6_); p7_=fmaf(w[7*8+jj],hvj,p7_);

// one recurrence step: VALU gather (DPP rors + one permlane32 pair),
// 64-fma tile dot (acc seeded in p0 = row l), fold xor1,xor2 (DPP) + xor16
// (permlane16 pair, calibrated pick), tanh. Updates h in place.
#define BSTEP(acc_expr)                                                      \
  {                                                                          \
    float hv0_ = h;                                                          \
    float hv1_ = DPPF(h, DPP_ROR4);                                          \
    float hv2_ = DPPF(h, DPP_ROR8);                                          \
    float hv3_ = DPPF(h, DPP_ROR12);                                         \
    float g_  = XOR32F(h);                                                   \
    float hv4_ = g_;                                                         \
    float hv5_ = DPPF(g_, DPP_ROR4);                                         \
    float hv6_ = DPPF(g_, DPP_ROR8);                                         \
    float hv7_ = DPPF(g_, DPP_ROR12);                                        \
    float p0_=(acc_expr), p1_=0.f,p2_=0.f,p3_=0.f,p4_=0.f,p5_=0.f,p6_=0.f,p7_=0.f; \
    DOTJ(0,hv0_); DOTJ(1,hv1_); DOTJ(2,hv2_); DOTJ(3,hv3_);                  \
    DOTJ(4,hv4_); DOTJ(5,hv5_); DOTJ(6,hv6_); DOTJ(7,hv7_);                  \
    p0_ += DPPF(p1_, DPP_XOR1); p2_ += DPPF(p3_, DPP_XOR1);                  \
    p4_ += DPPF(p5_, DPP_XOR1); p6_ += DPPF(p7_, DPP_XOR1);                  \
    p0_ += DPPF(p2_, DPP_XOR2); p4_ += DPPF(p6_, DPP_XOR2);                  \
    p0_ += XOR16F(p4_);                                                      \
    h = fast_tanh(p0_);                                                      \
  }
// ---------------------------------------------------------------------------

// pre_emb[v][n] = emb[v]·w_ih[0,n,:] + b_ih[0,n] + b_hh[0,n],  n = d*64+i
__global__ __launch_bounds__(128) void k_pre_emb(const float* __restrict__ emb,
    const float* __restrict__ w_ih, const float* __restrict__ b_ih, const float* __restrict__ b_hh,
    float* __restrict__ pe)
{
  const int v = blockIdx.x;
  const int n = threadIdx.x;           // 0..127
  const float* er = emb + (size_t)v*E;
  const float* wr = w_ih + (size_t)n*E;   // layer 0 rows
  float acc = b_ih[n] + b_hh[n];
  #pragma unroll
  for (int e=0;e<E;e+=4){
    float4 ev = *(const float4*)(er+e);
    float4 wv = *(const float4*)(wr+e);
    acc = fmaf(ev.x, wv.x, acc);
    acc = fmaf(ev.y, wv.y, acc);
    acc = fmaf(ev.z, wv.z, acc);
    acc = fmaf(ev.w, wv.w, acc);
  }
  pe[(size_t)v*128 + n] = acc;
}

// partial mean/max pools over S-chunks
__global__ __launch_bounds__(128) void k_pool(const int* __restrict__ x, const float* __restrict__ emb,
      float* __restrict__ psum, float* __restrict__ pmax)
{
  const int b = blockIdx.x, c = blockIdx.y, e = threadIdx.x;
  const int* xb = x + (size_t)b*S + c*(S/16);
  float s=0.f, m=-INFINITY;
  for (int k=0;k<S/16;++k){
    int v = xb[k];
    float val = emb[(size_t)v*E + e];
    s += val; m = fmaxf(m,val);
  }
  psum[((size_t)b*16 + c)*E + e] = s;
  pmax[((size_t)b*16 + c)*E + e] = m;
}

// layer-0 recurrence, fused gather: pre[t] = pe[x[t]] (pe is 409 KB -> L2-hot).
// One wave per (d,b) chain; all-VALU butterfly dot.
__global__ __attribute__((amdgpu_flat_work_group_size(64,64)))
__attribute__((amdgpu_waves_per_eu(1,1)))
void k_rec0(const int* __restrict__ x,
            const float* __restrict__ pe,
            ushort_t* __restrict__ y,
            const float* __restrict__ w_hh,
            float* __restrict__ hfin)
{
  const int c = blockIdx.x;           // 0..255
  const int d = c >> 7;
  const int b = c & 127;
  const int i = threadIdx.x;          // 0..63
  float w[64];
  bool pick16=false, pick32=false;
  const int ba32 = (i^32)<<2, ba16 = (i^16)<<2;
  (void)ba32; (void)ba16;
  CALIB_AND_LOAD_W(w_hh + (size_t)d*H*H);   // layer 0
  const int* xb = x + (size_t)b*S;
  const float* peb = pe + d*H + i;    // + v*128 per step
  ushort_t* yb = y + (size_t)b*S*(2*H) + d*H + i;
  const int fwd = (d==0);
  const int dt = fwd ? 1 : -1;
  int t = fwd ? 0 : S-1;

  int vx[8];                          // x values for t .. t+7
  #pragma unroll
  for (int k=0;k<8;++k) vx[k] = xb[clamp_t(t + k*dt)];
  float pl[4];                        // pe rows for t .. t+3
  #pragma unroll
  for (int k=0;k<4;++k) pl[k] = peb[(size_t)vx[k]*128];
  float h = 0.f;

#define STEP0(r) do {                                                        \
    float acc = pl[(r)&3];                                                   \
    pl[(r)&3] = peb[(size_t)vx[((r)+4)&7]*128];  /* row for t+4 */           \
    vx[(r)&7] = xb[clamp_t(t + 8*dt)];           /* x for t+8  */            \
    BSTEP(acc);                                                              \
    yb[(size_t)t*(2*H)] = f2bf(h);                                           \
    t += dt;                                                                 \
  } while(0)

  for (int tq=0; tq<S; tq+=8){
    STEP0(0); STEP0(1); STEP0(2); STEP0(3);
    STEP0(4); STEP0(5); STEP0(6); STEP0(7);
  }
#undef STEP0
  hfin[((size_t)d*B + b)*H + i] = h;
}

// layers 1,2 recurrence: pre streamed from HBM (134 MB), depth-8 prefetch
// ring; all-VALU butterfly dot; compile-time layer/write_y.
template<int LAYER, int WRITEY>
__global__ __attribute__((amdgpu_flat_work_group_size(64,64)))
__attribute__((amdgpu_waves_per_eu(1,1)))
void k_rec(const float* __restrict__ pre,
           ushort_t* __restrict__ y,
           const float* __restrict__ w_hh,
           float* __restrict__ hfin)
{
  const int c = blockIdx.x;           // 0..255
  const int d = c >> 7;
  const int b = c & 127;
  const int i = threadIdx.x;          // 0..63
  float w[64];
  bool pick16=false, pick32=false;
  const int ba32 = (i^32)<<2, ba16 = (i^16)<<2;
  (void)ba32; (void)ba16;
  CALIB_AND_LOAD_W(w_hh + (size_t)(LAYER*2+d)*H*H);
  const float* pb = pre + ((size_t)d*M + (size_t)b*S)*H + i;
  ushort_t* yb = y + (size_t)b*S*(2*H) + d*H + i;
  const int fwd = (d==0);
  const int dt = fwd ? 1 : -1;
  int t = fwd ? 0 : S-1;

  float pl[8];                        // pre values for t .. t+7
  #pragma unroll
  for (int k=0;k<8;++k) pl[k] = pb[(size_t)clamp_t(t + k*dt)*H];
  float h = 0.f;

#define STEPR(r) do {                                                        \
    float acc = pl[r];                                                       \
    pl[r] = pb[(size_t)clamp_t(t + 8*dt)*H];     /* value for t+8 */         \
    BSTEP(acc);                                                              \
    if (WRITEY) yb[(size_t)t*(2*H)] = f2bf(h);                               \
    t += dt;                                                                 \
  } while(0)

  for (int tq=0; tq<S; tq+=8){
    STEPR(0); STEPR(1); STEPR(2); STEPR(3);
    STEPR(4); STEPR(5); STEPR(6); STEPR(7);
  }
#undef STEPR
  hfin[((size_t)d*B + b)*H + i] = h;
}

// layers 1,2 input projection: [M,128]@[128,128]^T. Yin is bf16, W is fp32.
#define KC 32
__global__ __launch_bounds__(256) void k_gemm(const ushort_t* __restrict__ Yin,
     const float* __restrict__ w_ih, const float* __restrict__ b_ih,
     const float* __restrict__ b_hh, float* __restrict__ pre, int layer)
{
  __shared__ float sY[KC][132];
  __shared__ float sW[KC][132];
  const int tid = threadIdx.x;
  const int m0 = blockIdx.x * 128;
  const int tn = (tid & 15) * 8;
  const int tm = (tid >> 4) * 8;
  float acc[8][8];
  #pragma unroll
  for (int a=0;a<8;++a)
    #pragma unroll
    for (int q=0;q<8;++q) acc[a][q]=0.f;
  const float* Wb = w_ih + (size_t)layer*2*H*E;
  for (int kc=0; kc<E; kc+=KC){
    #pragma unroll
    for (int r=0;r<2;++r){
      int idx = r*256 + tid;     // 0..511
      int ym = idx >> 2;         // 0..127
      int yk = (idx & 3)*8;      // 0,8,16,24
      const ushort_t* p = Yin + (size_t)(m0+ym)*E + kc + yk;
      ushort4 a = *(const ushort4*)p;
      ushort4 bq = *(const ushort4*)(p+4);
      sY[yk+0][ym]=bf2f(a.x);  sY[yk+1][ym]=bf2f(a.y);  sY[yk+2][ym]=bf2f(a.z);  sY[yk+3][ym]=bf2f(a.w);
      sY[yk+4][ym]=bf2f(bq.x); sY[yk+5][ym]=bf2f(bq.y); sY[yk+6][ym]=bf2f(bq.z); sY[yk+7][ym]=bf2f(bq.w);
    }
    #pragma unroll
    for (int r=0;r<4;++r){
      int idx = r*256 + tid;     // 0..1023
      int wn = idx >> 3;         // 0..127
      int wk = (idx & 7)*4;      // 0..28
      float4 v = *(const float4*)(Wb + (size_t)wn*E + kc + wk);
      sW[wk+0][wn]=v.x; sW[wk+1][wn]=v.y; sW[wk+2][wn]=v.z; sW[wk+3][wn]=v.w;
    }
    __syncthreads();
    #pragma unroll 4
    for (int k=0;k<KC;++k){
      float4 a0 = *(const float4*)&sY[k][tm];
      float4 a1 = *(const float4*)&sY[k][tm+4];
      float4 b0 = *(const float4*)&sW[k][tn];
      float4 b1 = *(const float4*)&sW[k][tn+4];
      float am[8]={a0.x,a0.y,a0.z,a0.w,a1.x,a1.y,a1.z,a1.w};
      float bn[8]={b0.x,b0.y,b0.z,b0.w,b1.x,b1.y,b1.z,b1.w};
      #pragma unroll
      for (int mi=0;mi<8;++mi)
        #pragma unroll
        for (int ni=0;ni<8;++ni)
          acc[mi][ni] = fmaf(am[mi], bn[ni], acc[mi][ni]);
    }
    __syncthreads();
  }
  const int d = tn >> 6;
  const int i0 = tn & 63;
  float bias[8];
  #pragma unroll
  for (int ni=0;ni<8;++ni)
    bias[ni] = b_ih[(size_t)(layer*2+d)*H + i0+ni] + b_hh[(size_t)(layer*2+d)*H + i0+ni];
  #pragma unroll
  for (int mi=0;mi<8;++mi){
    size_t off = ((size_t)d*M + (m0+tm+mi))*H + i0;
    float4 o0 = make_float4(acc[mi][0]+bias[0], acc[mi][1]+bias[1], acc[mi][2]+bias[2], acc[mi][3]+bias[3]);
    float4 o1 = make_float4(acc[mi][4]+bias[4], acc[mi][5]+bias[5], acc[mi][6]+bias[6], acc[mi][7]+bias[7]);
    *(float4*)(pre + off)     = o0;
    *(float4*)(pre + off + 4) = o1;
  }
}

// final FC head; also reduces the 16 pool partials. fp32 in/out.
__global__ __launch_bounds__(128) void k_fc(const float* __restrict__ psum, const float* __restrict__ pmax,
    const float* __restrict__ hfin, const float* __restrict__ fc1_w, const float* __restrict__ fc1_b,
    const float* __restrict__ fc2_w, const float* __restrict__ fc2_b, float* __restrict__ out)
{
  const int b = blockIdx.x, tid = threadIdx.x;
  __shared__ __align__(16) float comb[384];
  __shared__ float red[2];
  float s=0.f, m=-INFINITY;
  #pragma unroll
  for (int c=0;c<16;++c){
    s += psum[((size_t)b*16+c)*E + tid];
    m = fmaxf(m, pmax[((size_t)b*16+c)*E + tid]);
  }
  comb[128+tid] = s*(1.f/2048.f);
  comb[256+tid] = m;
  comb[tid] = (tid<64) ? hfin[(size_t)b*H + tid] : hfin[((size_t)B + b)*H + (tid-64)];
  __syncthreads();
  float acc = fc1_b[tid];
  const float4* wrow = (const float4*)(fc1_w + (size_t)tid*384);
  const float4* cb = (const float4*)comb;
  #pragma unroll 8
  for (int k=0;k<96;++k){
    float4 wv = wrow[k]; float4 cv = cb[k];
    acc = fmaf(wv.x,cv.x,acc); acc = fmaf(wv.y,cv.y,acc);
    acc = fmaf(wv.z,cv.z,acc); acc = fmaf(wv.w,cv.w,acc);
  }
  acc = fmaxf(acc, 0.f);
  float p = acc * fc2_w[tid];
  #pragma unroll
  for (int off=32; off>0; off>>=1) p += __shfl_down(p, off);
  if ((tid & 63)==0) red[tid>>6] = p;
  __syncthreads();
  if (tid==0) out[b] = red[0] + red[1] + fc2_b[0];
}

extern "C" void kernel_launch(void* const* d_in, const int* in_sizes, int n_in,
                              void* d_out, int out_size, void* d_ws, size_t ws_size,
                              hipStream_t stream)
{
  const int*   x     = (const int*)  d_in[0];
  const float* emb   = (const float*)d_in[1];
  const float* w_ih  = (const float*)d_in[2];
  const float* w_hh  = (const float*)d_in[3];
  const float* b_ih  = (const float*)d_in[4];
  const float* b_hh  = (const float*)d_in[5];
  const float* fc1_w = (const float*)d_in[6];
  const float* fc1_b = (const float*)d_in[7];
  const float* fc2_w = (const float*)d_in[8];
  const float* fc2_b = (const float*)d_in[9];
  float* out = (float*)d_out;

  // workspace: keep under ~204 MB
  char* ws = (char*)d_ws;
  float*    pre  = (float*)(ws);                                     // 2*M*H f32  = 134.2 MB (layers 1,2 only)
  ushort_t* y    = (ushort_t*)(ws + (size_t)2*M*H*4);                // M*128 bf16 =  67.1 MB
  float*    pe   = (float*)(ws + (size_t)2*M*H*4 + (size_t)M*128*2); // V*128 f32
  float*    psum = pe   + (size_t)V*128;                             // B*16*E f32
  float*    pmax = psum + (size_t)B*16*E;                            // B*16*E f32
  float*    hfin = pmax + (size_t)B*16*E;                            // 2*B*H f32

  k_pre_emb<<<V, 128, 0, stream>>>(emb, w_ih, b_ih, b_hh, pe);
  k_pool<<<dim3(B,16), 128, 0, stream>>>(x, emb, psum, pmax);
  k_rec0<<<256, 64, 0, stream>>>(x, pe, y, w_hh, hfin);
  k_gemm<<<M/128, 256, 0, stream>>>(y, w_ih, b_ih, b_hh, pre, 1);
  k_rec<1,1><<<256, 64, 0, stream>>>(pre, y, w_hh, hfin);
  k_gemm<<<M/128, 256, 0, stream>>>(y, w_ih, b_ih, b_hh, pre, 2);
  k_rec<2,0><<<256, 64, 0, stream>>>(pre, y, w_hh, hfin);
  k_fc<<<B, 128, 0, stream>>>(psum, pmax, hfin, fc1_w, fc1_b, fc2_w, fc2_b, out);
}